// Round 3
// baseline (11495.859 us; speedup 1.0000x reference)
//
#include <hip/hip_runtime.h>
#include <hip/hip_bf16.h>

typedef __hip_bfloat16 bf16;

#define NB 8
#define NQ 900
#define DM 256
#define NHEADS 8
#define DHEAD 32
#define NFF 1024
#define NLAY 6
#define NS 13294
#define BQ (NB*NQ)            // 7200
#define LN_EPS 1e-5f
#define ATT_SCALE 0.17677669529663687f   // 1/sqrt(32)

__device__ __forceinline__ float bfd(const bf16* p, size_t i){ return __bfloat162float(p[i]); }

// mode: 0 = fp32 (internal), 1 = bf16 (internal), 2 = external (dtype per flag)
__device__ __forceinline__ float ldv(const void* p, size_t i, int mode, bool extF32)
{
    if (mode == 0) return ((const float*)p)[i];
    if (mode == 1) return bfd((const bf16*)p, i);
    return extF32 ? ((const float*)p)[i] : bfd((const bf16*)p, i);
}

// ---------------------------------------------------------------------------
// dtype detector: read first 2048 u16 words of tgt as bf16. True bf16 N(0,1)
// data -> max|v| < ~6. fp32 bit-halves -> wild exponents / NaN. flag=1 => f32.
// ---------------------------------------------------------------------------
__global__ __launch_bounds__(256) void detect_dtype(const void* __restrict__ tgt,
        float* __restrict__ flag)
{
    __shared__ float red[256];
    int t = threadIdx.x;
    const unsigned short* u = (const unsigned short*)tgt;
    float m = 0.f;
    for (int i = t; i < 2048; i += 256) {
        unsigned int bits = ((unsigned int)u[i]) << 16;
        float v = fabsf(__uint_as_float(bits));
        if (!isfinite(v)) v = 1e30f;
        m = fmaxf(m, v);
    }
    red[t] = m;
    __syncthreads();
    for (int st = 128; st; st >>= 1) {
        if (t < st) red[t] = fmaxf(red[t], red[t + st]);
        __syncthreads();
    }
    if (t == 0) flag[0] = (red[0] > 1e8f) ? 1.f : 0.f;
}

// ---------------------------------------------------------------------------
// GEMM: C[M,N] = A[M,K] @ W[N,K]^T + bias[N]  (optional relu)
// 64x64 tile, 256 threads, 4x4 per thread, BK=16. N multiple of 64.
// A dtype per amode; W/bias always external (mode 2); C per cmode (0/1).
// ---------------------------------------------------------------------------
__global__ __launch_bounds__(256) void gemm_bias(const void* __restrict__ A, int amode,
        const void* __restrict__ W, const void* __restrict__ bias,
        void* __restrict__ C, int cmode, int M, int N, int K, int relu,
        const float* __restrict__ flagp)
{
    const bool ef = flagp[0] > 0.5f;
    __shared__ __align__(16) float As[16][64];
    __shared__ __align__(16) float Bs[16][64];
    const int tid = threadIdx.x;
    const int m0 = blockIdx.y * 64, n0 = blockIdx.x * 64;
    const int tr = tid >> 4, tc = tid & 15;
    const int lrow = tid >> 2, lk = (tid & 3) * 4;
    float acc[4][4] = {};
    for (int k0 = 0; k0 < K; k0 += 16) {
        int m = m0 + lrow;
        if (m < M) {
            size_t ai = (size_t)m * K + k0 + lk;
            As[lk+0][lrow] = ldv(A, ai+0, amode, ef);
            As[lk+1][lrow] = ldv(A, ai+1, amode, ef);
            As[lk+2][lrow] = ldv(A, ai+2, amode, ef);
            As[lk+3][lrow] = ldv(A, ai+3, amode, ef);
        } else {
            As[lk+0][lrow] = 0.f; As[lk+1][lrow] = 0.f;
            As[lk+2][lrow] = 0.f; As[lk+3][lrow] = 0.f;
        }
        size_t wi = (size_t)(n0 + lrow) * K + k0 + lk;
        Bs[lk+0][lrow] = ldv(W, wi+0, 2, ef);
        Bs[lk+1][lrow] = ldv(W, wi+1, 2, ef);
        Bs[lk+2][lrow] = ldv(W, wi+2, 2, ef);
        Bs[lk+3][lrow] = ldv(W, wi+3, 2, ef);
        __syncthreads();
        #pragma unroll
        for (int kk = 0; kk < 16; kk++) {
            float4 ra = *(const float4*)&As[kk][tr*4];
            float4 rb = *(const float4*)&Bs[kk][tc*4];
            acc[0][0] += ra.x*rb.x; acc[0][1] += ra.x*rb.y; acc[0][2] += ra.x*rb.z; acc[0][3] += ra.x*rb.w;
            acc[1][0] += ra.y*rb.x; acc[1][1] += ra.y*rb.y; acc[1][2] += ra.y*rb.z; acc[1][3] += ra.y*rb.w;
            acc[2][0] += ra.z*rb.x; acc[2][1] += ra.z*rb.y; acc[2][2] += ra.z*rb.z; acc[2][3] += ra.z*rb.w;
            acc[3][0] += ra.w*rb.x; acc[3][1] += ra.w*rb.y; acc[3][2] += ra.w*rb.z; acc[3][3] += ra.w*rb.w;
        }
        __syncthreads();
    }
    float bv[4];
    #pragma unroll
    for (int j = 0; j < 4; j++) bv[j] = ldv(bias, n0 + tc*4 + j, 2, ef);
    #pragma unroll
    for (int i = 0; i < 4; i++) {
        int m = m0 + tr*4 + i;
        if (m >= M) continue;
        #pragma unroll
        for (int j = 0; j < 4; j++) {
            float v = acc[i][j] + bv[j];
            if (relu) v = fmaxf(v, 0.f);
            size_t ci = (size_t)m * N + n0 + tc*4 + j;
            if (cmode == 0) ((float*)C)[ci] = v;
            else            ((bf16*)C)[ci] = __float2bfloat16(v);
        }
    }
}

// ---------------------------------------------------------------------------
// o = a + query_pos  (a per amode; qp external)
// ---------------------------------------------------------------------------
__global__ __launch_bounds__(256) void add_qpos(const void* __restrict__ a, int amode,
        const void* __restrict__ qp, float* __restrict__ o, const float* __restrict__ flagp)
{
    const bool ef = flagp[0] > 0.5f;
    int i = blockIdx.x * 256 + threadIdx.x;
    o[i] = ldv(a, i, amode, ef) + ldv(qp, i, 2, ef);
}

// ---------------------------------------------------------------------------
// MHA: one block (128 threads) per (b,h,q). qkv bf16 [B,Q,768] = q|k|v.
// ---------------------------------------------------------------------------
__global__ __launch_bounds__(128) void mha_kernel(const bf16* __restrict__ qkv,
        float* __restrict__ out)
{
    int idx = blockIdx.x;
    int q = idx % NQ; int h = (idx / NQ) % NHEADS; int b = idx / (NQ * NHEADS);
    __shared__ float qs[DHEAD];
    __shared__ float sc[NQ];
    __shared__ float red[128];
    __shared__ float part[4][DHEAD];
    const bf16* base = qkv + (size_t)b * NQ * 768;
    int tid = threadIdx.x;
    if (tid < DHEAD) qs[tid] = bfd(base, (size_t)q * 768 + h * DHEAD + tid);
    __syncthreads();
    float lmax = -1e30f;
    for (int k = tid; k < NQ; k += 128) {
        const bf16* kp = base + (size_t)k * 768 + 256 + h * DHEAD;
        float s = 0.f;
        #pragma unroll
        for (int d = 0; d < DHEAD; d++) s += qs[d] * __bfloat162float(kp[d]);
        s *= ATT_SCALE;
        sc[k] = s;
        lmax = fmaxf(lmax, s);
    }
    red[tid] = lmax;
    __syncthreads();
    for (int st = 64; st > 0; st >>= 1) {
        if (tid < st) red[tid] = fmaxf(red[tid], red[tid + st]);
        __syncthreads();
    }
    float gmax = red[0];
    __syncthreads();
    float lsum = 0.f;
    for (int k = tid; k < NQ; k += 128) {
        float e = __expf(sc[k] - gmax);
        sc[k] = e;
        lsum += e;
    }
    red[tid] = lsum;
    __syncthreads();
    for (int st = 64; st > 0; st >>= 1) {
        if (tid < st) red[tid] += red[tid + st];
        __syncthreads();
    }
    float inv = 1.f / red[0];
    int d = tid & 31, g = tid >> 5;
    float acc = 0.f;
    for (int k = g; k < NQ; k += 4)
        acc += sc[k] * bfd(base, (size_t)k * 768 + 512 + h * DHEAD + d);
    part[g][d] = acc;
    __syncthreads();
    if (tid < 32) {
        float o = (part[0][d] + part[1][d] + part[2][d] + part[3][d]) * inv;
        out[((size_t)(b * NQ + q)) * DM + h * DHEAD + d] = o;
    }
}

// ---------------------------------------------------------------------------
// out = LN(res + x)*g + b ; optional mirror write into d_out (dtype per flag).
// out may alias res. One 256-thread block per row.
// ---------------------------------------------------------------------------
__global__ __launch_bounds__(256) void ln_kernel(const float* res,
        const float* __restrict__ x, const void* __restrict__ gw,
        const void* __restrict__ bw, float* out, void* __restrict__ oout,
        size_t obase, const float* __restrict__ flagp)
{
    const bool ef = flagp[0] > 0.5f;
    int row = blockIdx.x, d = threadIdx.x;
    size_t off = (size_t)row * DM + d;
    float v = res[off] + x[off];
    __shared__ float red[256];
    red[d] = v;
    __syncthreads();
    for (int st = 128; st > 0; st >>= 1) {
        if (d < st) red[d] += red[d + st];
        __syncthreads();
    }
    float mu = red[0] * (1.f / DM);
    __syncthreads();
    float dv = v - mu;
    red[d] = dv * dv;
    __syncthreads();
    for (int st = 128; st > 0; st >>= 1) {
        if (d < st) red[d] += red[d + st];
        __syncthreads();
    }
    float var = red[0] * (1.f / DM);
    float o = dv * rsqrtf(var + LN_EPS) * ldv(gw, d, 2, ef) + ldv(bw, d, 2, ef);
    out[off] = o;
    if (oout) {
        if (ef) ((float*)oout)[obase + off] = o;
        else    ((bf16*)oout)[obase + off] = __float2bfloat16(o);
    }
}

// ---------------------------------------------------------------------------
__global__ __launch_bounds__(256) void aw_softmax(float* __restrict__ aw)
{
    int i = blockIdx.x * 256 + threadIdx.x;
    if (i >= BQ * NHEADS) return;
    float* p = aw + (size_t)i * 16;
    float mx = -1e30f;
    #pragma unroll
    for (int j = 0; j < 16; j++) mx = fmaxf(mx, p[j]);
    float s = 0.f;
    #pragma unroll
    for (int j = 0; j < 16; j++) { float e = __expf(p[j] - mx); p[j] = e; s += e; }
    float inv = 1.f / s;
    #pragma unroll
    for (int j = 0; j < 16; j++) p[j] *= inv;
}

// ---------------------------------------------------------------------------
// MSDA sampling. One block (256 thr) per (b,q); thread = (head h, dim d).
// value bf16 internal; off/aw fp32 internal; refp/vr external.
// ---------------------------------------------------------------------------
__global__ __launch_bounds__(256) void msda_sample(const bf16* __restrict__ value,
        const float* __restrict__ off, const float* __restrict__ aw,
        const void* __restrict__ refp, const void* __restrict__ vr,
        float* __restrict__ out, const float* __restrict__ flagp)
{
    const bool ef = flagp[0] > 0.5f;
    int bq = blockIdx.x; int b = bq / NQ;
    int tid = threadIdx.x; int h = tid >> 5, d = tid & 31;
    __shared__ float sOff[256];
    __shared__ float sAw[128];
    __shared__ float sref[2];
    __shared__ float svr[8];
    sOff[tid] = off[(size_t)bq * 256 + tid];
    if (tid < 128) sAw[tid] = aw[(size_t)bq * 128 + tid];
    if (tid < 2)   sref[tid] = ldv(refp, bq * 2 + tid, 2, ef);
    if (tid < 8)   svr[tid]  = ldv(vr, b * 8 + tid, 2, ef);
    __syncthreads();
    const bf16* vb = value + (size_t)b * NS * DM + h * DHEAD + d;
    const int HS[4] = {100, 50, 25, 13};
    const int ST[4] = {0, 10000, 12500, 13125};
    float acc = 0.f;
    #pragma unroll
    for (int lvl = 0; lvl < 4; lvl++) {
        int W_ = HS[lvl], H_ = HS[lvl], st = ST[lvl];
        float rx = sref[0] * svr[lvl*2 + 0] * (float)W_;
        float ry = sref[1] * svr[lvl*2 + 1] * (float)H_;
        #pragma unroll
        for (int p = 0; p < 4; p++) {
            int oi = h * 32 + lvl * 8 + p * 2;
            float x = fminf(fmaxf(rx + sOff[oi]     - 0.5f, -4.f), (float)W_ + 4.f);
            float y = fminf(fmaxf(ry + sOff[oi + 1] - 0.5f, -4.f), (float)H_ + 4.f);
            float x0f = floorf(x), y0f = floorf(y);
            float wx = x - x0f, wy = y - y0f;
            int x0 = (int)x0f, y0 = (int)y0f;
            int x1i = x0 + 1, y1i = y0 + 1;
            bool vx0 = (x0 >= 0) && (x0 < W_), vx1 = (x1i >= 0) && (x1i < W_);
            bool vy0 = (y0 >= 0) && (y0 < H_), vy1 = (y1i >= 0) && (y1i < H_);
            float g = 0.f;
            if (vy0) {
                int rowo = (st + y0 * W_) * DM;
                if (vx0) g += (1.f - wx) * (1.f - wy) * __bfloat162float(vb[rowo + x0  * DM]);
                if (vx1) g += wx         * (1.f - wy) * __bfloat162float(vb[rowo + x1i * DM]);
            }
            if (vy1) {
                int rowo = (st + y1i * W_) * DM;
                if (vx0) g += (1.f - wx) * wy * __bfloat162float(vb[rowo + x0  * DM]);
                if (vx1) g += wx         * wy * __bfloat162float(vb[rowo + x1i * DM]);
            }
            acc += g * sAw[h * 16 + lvl * 4 + p];
        }
    }
    out[(size_t)bq * DM + tid] = acc;
}

// ---------------------------------------------------------------------------
// inter_refs: reference_points repeated NLAY times, written in flag dtype at
// element offset NLAY*BQ*DM of d_out.
// ---------------------------------------------------------------------------
__global__ __launch_bounds__(256) void copy_refs(const void* __restrict__ refp,
        void* __restrict__ out, const float* __restrict__ flagp)
{
    const bool ef = flagp[0] > 0.5f;
    int i = blockIdx.x * 256 + threadIdx.x;
    if (i >= NLAY * BQ * 2) return;
    float v = ldv(refp, i % (BQ * 2), 2, ef);
    size_t oi = (size_t)NLAY * BQ * DM + i;
    if (ef) ((float*)out)[oi] = v;
    else    ((bf16*)out)[oi] = __float2bfloat16(v);
}

// ---------------------------------------------------------------------------
extern "C" void kernel_launch(void* const* d_in, const int* in_sizes, int n_in,
                              void* d_out, int out_size, void* d_ws, size_t ws_size,
                              hipStream_t stream)
{
    const void* tgt     = d_in[0];
    const void* refp    = d_in[1];
    const void* memory  = d_in[2];
    const void* vr      = d_in[5];
    const void* qp      = d_in[6];
    const void* sa_in_w = d_in[7];
    const void* sa_in_b = d_in[8];
    const void* sa_out_w= d_in[9];
    const void* sa_out_b= d_in[10];
    const void* n1_g    = d_in[11];
    const void* n1_b    = d_in[12];
    const void* n2_g    = d_in[13];
    const void* n2_b    = d_in[14];
    const void* n3_g    = d_in[15];
    const void* n3_b    = d_in[16];
    const void* vp_w    = d_in[17];
    const void* vp_b    = d_in[18];
    const void* so_w    = d_in[19];
    const void* so_b    = d_in[20];
    const void* aw_w    = d_in[21];
    const void* aw_b    = d_in[22];
    const void* op_w    = d_in[23];
    const void* op_b    = d_in[24];
    const void* ff1_w   = d_in[25];
    const void* ff1_b   = d_in[26];
    const void* ff2_w   = d_in[27];
    const void* ff2_b   = d_in[28];

    // ---- workspace layout ----
    char* w = (char*)d_ws;
    float* flagp  = (float*)w;  w += 256;
    bf16*  value  = (bf16*)w;   w += (size_t)NB * NS * DM * 2;   // 54.45 MB
    float* outbuf = (float*)w;  w += (size_t)BQ * DM * 4;
    float* x1samp = (float*)w;  w += (size_t)BQ * DM * 4;        // x1, later samp
    bf16*  bigb   = (bf16*)w;   w += (size_t)BQ * NFF * 2;       // qkv / ffn hidden
    float* attoff = (float*)w;  w += (size_t)BQ * DM * 4;        // attn, later offsets
    float* t2     = (float*)w;  w += (size_t)BQ * DM * 4;
    float* awb    = (float*)w;  w += (size_t)BQ * 128 * 4;

    const int gy = (BQ + 63) / 64;      // 113
    const int MV = NB * NS;             // 106352

    // 0) detect external dtype
    detect_dtype<<<1, 256, 0, stream>>>(tgt, flagp);

    // 1) value projection (layer-invariant)
    gemm_bias<<<dim3(DM/64, (MV + 63) / 64), 256, 0, stream>>>(
        memory, 2, vp_w, vp_b, value, 1, MV, DM, DM, 0, flagp);

    // 2) inter_refs output
    copy_refs<<<(NLAY * BQ * 2 + 255) / 256, 256, 0, stream>>>(refp, d_out, flagp);

    for (int l = 0; l < NLAY; l++) {
        // x1 = output + query_pos
        if (l == 0) add_qpos<<<BQ * DM / 256, 256, 0, stream>>>(tgt, 2, qp, x1samp, flagp);
        else        add_qpos<<<BQ * DM / 256, 256, 0, stream>>>(outbuf, 0, qp, x1samp, flagp);

        // self-attention
        gemm_bias<<<dim3(768/64, gy), 256, 0, stream>>>(
            x1samp, 0, sa_in_w, sa_in_b, bigb, 1, BQ, 768, DM, 0, flagp);
        mha_kernel<<<NB * NHEADS * NQ, 128, 0, stream>>>(bigb, attoff);
        gemm_bias<<<dim3(DM/64, gy), 256, 0, stream>>>(
            attoff, 0, sa_out_w, sa_out_b, t2, 0, BQ, DM, DM, 0, flagp);
        ln_kernel<<<BQ, 256, 0, stream>>>(x1samp, t2, n1_g, n1_b, outbuf,
                                          nullptr, 0, flagp);

        // MSDA
        gemm_bias<<<dim3(DM/64, gy), 256, 0, stream>>>(
            outbuf, 0, so_w, so_b, attoff, 0, BQ, DM, DM, 0, flagp);
        gemm_bias<<<dim3(128/64, gy), 256, 0, stream>>>(
            outbuf, 0, aw_w, aw_b, awb, 0, BQ, 128, DM, 0, flagp);
        aw_softmax<<<(BQ * NHEADS + 255) / 256, 256, 0, stream>>>(awb);
        msda_sample<<<BQ, 256, 0, stream>>>(value, attoff, awb, refp, vr, x1samp, flagp);
        gemm_bias<<<dim3(DM/64, gy), 256, 0, stream>>>(
            x1samp, 0, op_w, op_b, t2, 0, BQ, DM, DM, 0, flagp);
        ln_kernel<<<BQ, 256, 0, stream>>>(outbuf, t2, n2_g, n2_b, outbuf,
                                          nullptr, 0, flagp);

        // FFN
        gemm_bias<<<dim3(NFF/64, gy), 256, 0, stream>>>(
            outbuf, 0, ff1_w, ff1_b, bigb, 1, BQ, NFF, DM, 1, flagp);
        gemm_bias<<<dim3(DM/64, gy), 256, 0, stream>>>(
            bigb, 1, ff2_w, ff2_b, t2, 0, BQ, DM, NFF, 0, flagp);
        ln_kernel<<<BQ, 256, 0, stream>>>(outbuf, t2, n3_g, n3_b, outbuf,
                                          d_out, (size_t)l * BQ * DM, flagp);
    }
}

// Round 4
// 5576.860 us; speedup vs baseline: 2.0613x; 2.0613x over previous
//
#include <hip/hip_runtime.h>
#include <hip/hip_bf16.h>

typedef __hip_bfloat16 bf16;

#define NB 8
#define NQ 900
#define DM 256
#define NHEADS 8
#define DHEAD 32
#define NFF 1024
#define NLAY 6
#define NS 13294
#define BQ (NB*NQ)            // 7200
#define LN_EPS 1e-5f
#define ATT_SCALE 0.17677669529663687f   // 1/sqrt(32)

__device__ __forceinline__ float bfd(const bf16* p, size_t i){ return __bfloat162float(p[i]); }

// mode: 0 = fp32 (internal), 1 = bf16 (internal), 2 = external (dtype per flag)
__device__ __forceinline__ float ldv(const void* p, size_t i, int mode, bool extF32)
{
    if (mode == 0) return ((const float*)p)[i];
    if (mode == 1) return bfd((const bf16*)p, i);
    return extF32 ? ((const float*)p)[i] : bfd((const bf16*)p, i);
}

// unpack 8 bf16 (16B) to floats
__device__ __forceinline__ void unpack8(uint4 u, float* t)
{
    t[0] = __uint_as_float((u.x & 0xffffu) << 16);
    t[1] = __uint_as_float(u.x & 0xffff0000u);
    t[2] = __uint_as_float((u.y & 0xffffu) << 16);
    t[3] = __uint_as_float(u.y & 0xffff0000u);
    t[4] = __uint_as_float((u.z & 0xffffu) << 16);
    t[5] = __uint_as_float(u.z & 0xffff0000u);
    t[6] = __uint_as_float((u.w & 0xffffu) << 16);
    t[7] = __uint_as_float(u.w & 0xffff0000u);
}

// ---------------------------------------------------------------------------
// dtype detector (kept from round 3; inputs proved fp32 but keep it robust)
// ---------------------------------------------------------------------------
__global__ __launch_bounds__(256) void detect_dtype(const void* __restrict__ tgt,
        float* __restrict__ flag)
{
    __shared__ float red[256];
    int t = threadIdx.x;
    const unsigned short* u = (const unsigned short*)tgt;
    float m = 0.f;
    for (int i = t; i < 2048; i += 256) {
        unsigned int bits = ((unsigned int)u[i]) << 16;
        float v = fabsf(__uint_as_float(bits));
        if (!isfinite(v)) v = 1e30f;
        m = fmaxf(m, v);
    }
    red[t] = m;
    __syncthreads();
    for (int st = 128; st; st >>= 1) {
        if (t < st) red[t] = fmaxf(red[t], red[t + st]);
        __syncthreads();
    }
    if (t == 0) flag[0] = (red[0] > 1e8f) ? 1.f : 0.f;
}

// ---------------------------------------------------------------------------
// GEMM: C[M,N] = A[M,K] @ W[N,K]^T + bias[N]  (optional relu)  — unchanged
// ---------------------------------------------------------------------------
__global__ __launch_bounds__(256) void gemm_bias(const void* __restrict__ A, int amode,
        const void* __restrict__ W, const void* __restrict__ bias,
        void* __restrict__ C, int cmode, int M, int N, int K, int relu,
        const float* __restrict__ flagp)
{
    const bool ef = flagp[0] > 0.5f;
    __shared__ __align__(16) float As[16][64];
    __shared__ __align__(16) float Bs[16][64];
    const int tid = threadIdx.x;
    const int m0 = blockIdx.y * 64, n0 = blockIdx.x * 64;
    const int tr = tid >> 4, tc = tid & 15;
    const int lrow = tid >> 2, lk = (tid & 3) * 4;
    float acc[4][4] = {};
    for (int k0 = 0; k0 < K; k0 += 16) {
        int m = m0 + lrow;
        if (m < M) {
            size_t ai = (size_t)m * K + k0 + lk;
            As[lk+0][lrow] = ldv(A, ai+0, amode, ef);
            As[lk+1][lrow] = ldv(A, ai+1, amode, ef);
            As[lk+2][lrow] = ldv(A, ai+2, amode, ef);
            As[lk+3][lrow] = ldv(A, ai+3, amode, ef);
        } else {
            As[lk+0][lrow] = 0.f; As[lk+1][lrow] = 0.f;
            As[lk+2][lrow] = 0.f; As[lk+3][lrow] = 0.f;
        }
        size_t wi = (size_t)(n0 + lrow) * K + k0 + lk;
        Bs[lk+0][lrow] = ldv(W, wi+0, 2, ef);
        Bs[lk+1][lrow] = ldv(W, wi+1, 2, ef);
        Bs[lk+2][lrow] = ldv(W, wi+2, 2, ef);
        Bs[lk+3][lrow] = ldv(W, wi+3, 2, ef);
        __syncthreads();
        #pragma unroll
        for (int kk = 0; kk < 16; kk++) {
            float4 ra = *(const float4*)&As[kk][tr*4];
            float4 rb = *(const float4*)&Bs[kk][tc*4];
            acc[0][0] += ra.x*rb.x; acc[0][1] += ra.x*rb.y; acc[0][2] += ra.x*rb.z; acc[0][3] += ra.x*rb.w;
            acc[1][0] += ra.y*rb.x; acc[1][1] += ra.y*rb.y; acc[1][2] += ra.y*rb.z; acc[1][3] += ra.y*rb.w;
            acc[2][0] += ra.z*rb.x; acc[2][1] += ra.z*rb.y; acc[2][2] += ra.z*rb.z; acc[2][3] += ra.z*rb.w;
            acc[3][0] += ra.w*rb.x; acc[3][1] += ra.w*rb.y; acc[3][2] += ra.w*rb.z; acc[3][3] += ra.w*rb.w;
        }
        __syncthreads();
    }
    float bv[4];
    #pragma unroll
    for (int j = 0; j < 4; j++) bv[j] = ldv(bias, n0 + tc*4 + j, 2, ef);
    #pragma unroll
    for (int i = 0; i < 4; i++) {
        int m = m0 + tr*4 + i;
        if (m >= M) continue;
        #pragma unroll
        for (int j = 0; j < 4; j++) {
            float v = acc[i][j] + bv[j];
            if (relu) v = fmaxf(v, 0.f);
            size_t ci = (size_t)m * N + n0 + tc*4 + j;
            if (cmode == 0) ((float*)C)[ci] = v;
            else            ((bf16*)C)[ci] = __float2bfloat16(v);
        }
    }
}

// ---------------------------------------------------------------------------
__global__ __launch_bounds__(256) void add_qpos(const void* __restrict__ a, int amode,
        const void* __restrict__ qp, float* __restrict__ o, const float* __restrict__ flagp)
{
    const bool ef = flagp[0] > 0.5f;
    int i = blockIdx.x * 256 + threadIdx.x;
    o[i] = ldv(a, i, amode, ef) + ldv(qp, i, 2, ef);
}

// ---------------------------------------------------------------------------
// Flash MHA. grid (qtile=15, h=8, b=8), 256 threads.
// qkv bf16 [B,Q,768] = q|k|v. Q in regs (pre-scaled); K/V tiles in LDS;
// online softmax (m,l,alpha in LDS); O in regs; out fp32 [BQ,256].
// ---------------------------------------------------------------------------
__global__ __launch_bounds__(256) void mha_flash(const bf16* __restrict__ qkv,
        float* __restrict__ out)
{
    const int qt = blockIdx.x, h = blockIdx.y, b = blockIdx.z;
    const int q0 = qt * 64;
    const int nq = min(64, NQ - q0);
    const int tid = threadIdx.x;
    const int qi = tid & 63;        // score-phase query row
    const int kg = tid >> 6;        // score-phase key group (16 keys)
    const int qo = tid >> 2;        // pv-phase query row
    const int dg = tid & 3;         // pv-phase dim group (8 floats)

    __shared__ __align__(16) float Ks[64][36];   // stride 36 floats = 144B (16B-aligned rows)
    __shared__ __align__(16) float Vs[64][36];
    __shared__ float Ps[64][65];                 // stride 65: (qi+k)%32 banks, 2-way free
    __shared__ float sred[4][64];
    __shared__ float mS[64], lS[64], aS[64];

    const bf16* base = qkv + (size_t)b * NQ * 768;
    const int row = tid >> 2, c0 = (tid & 3) * 8;

    // ---- stage Q tile into Ks (scaled), then load into registers ----
    {
        float t[8];
        if (q0 + row < NQ) {
            uint4 u = *(const uint4*)(base + (size_t)(q0 + row) * 768 + h * DHEAD + c0);
            unpack8(u, t);
        } else {
            #pragma unroll
            for (int i = 0; i < 8; i++) t[i] = 0.f;
        }
        #pragma unroll
        for (int i = 0; i < 8; i++) Ks[row][c0 + i] = t[i] * ATT_SCALE;
    }
    if (tid < 64) { mS[tid] = -1e30f; lS[tid] = 0.f; }
    __syncthreads();
    float qreg[32];
    #pragma unroll
    for (int d4 = 0; d4 < 8; d4++) {
        float4 v = *(const float4*)&Ks[qi][d4 * 4];
        qreg[d4*4+0] = v.x; qreg[d4*4+1] = v.y; qreg[d4*4+2] = v.z; qreg[d4*4+3] = v.w;
    }
    float O[8] = {0.f,0.f,0.f,0.f,0.f,0.f,0.f,0.f};

    for (int k0 = 0; k0 < NQ; k0 += 64) {
        __syncthreads();   // protect Ks/Vs/Ps from previous phase
        // ---- stage K,V tile ----
        {
            float tk[8], tv[8];
            if (k0 + row < NQ) {
                const bf16* rp = base + (size_t)(k0 + row) * 768 + h * DHEAD + c0;
                uint4 uk = *(const uint4*)(rp + 256);
                uint4 uv = *(const uint4*)(rp + 512);
                unpack8(uk, tk); unpack8(uv, tv);
            } else {
                #pragma unroll
                for (int i = 0; i < 8; i++) { tk[i] = 0.f; tv[i] = 0.f; }
            }
            #pragma unroll
            for (int i = 0; i < 8; i++) { Ks[row][c0+i] = tk[i]; Vs[row][c0+i] = tv[i]; }
        }
        __syncthreads();
        // ---- scores: thread (qi, kg) computes 16 scores ----
        const int kvalid = NQ - k0;   // may exceed 64 (=> all valid)
        float s[16];
        #pragma unroll
        for (int j = 0; j < 16; j++) {
            int kj = kg * 16 + j;
            float acc = 0.f;
            #pragma unroll
            for (int d4 = 0; d4 < 8; d4++) {
                float4 kv = *(const float4*)&Ks[kj][d4 * 4];
                acc += qreg[d4*4+0]*kv.x + qreg[d4*4+1]*kv.y
                     + qreg[d4*4+2]*kv.z + qreg[d4*4+3]*kv.w;
            }
            s[j] = (kj < kvalid) ? acc : -1e30f;
        }
        float tmax = s[0];
        #pragma unroll
        for (int j = 1; j < 16; j++) tmax = fmaxf(tmax, s[j]);
        sred[kg][qi] = tmax;
        __syncthreads();
        if (tid < 64) {
            float tm = fmaxf(fmaxf(sred[0][tid], sred[1][tid]),
                             fmaxf(sred[2][tid], sred[3][tid]));
            float mnew = fmaxf(mS[tid], tm);
            aS[tid] = __expf(mS[tid] - mnew);
            mS[tid] = mnew;
        }
        __syncthreads();
        float mq = mS[qi];
        float psum = 0.f;
        #pragma unroll
        for (int j = 0; j < 16; j++) {
            float p = __expf(s[j] - mq);
            Ps[qi][kg * 16 + j] = p;
            psum += p;
        }
        sred[kg][qi] = psum;
        __syncthreads();
        if (tid < 64)
            lS[tid] = lS[tid] * aS[tid]
                    + sred[0][tid] + sred[1][tid] + sred[2][tid] + sred[3][tid];
        // ---- O update: thread (qo, dg) owns 8 dims of query qo ----
        float alpha = aS[qo];
        #pragma unroll
        for (int d = 0; d < 8; d++) O[d] *= alpha;
        #pragma unroll 4
        for (int k = 0; k < 64; k++) {
            float pv = Ps[qo][k];
            float4 v0 = *(const float4*)&Vs[k][dg * 8];
            float4 v1 = *(const float4*)&Vs[k][dg * 8 + 4];
            O[0] += pv * v0.x; O[1] += pv * v0.y; O[2] += pv * v0.z; O[3] += pv * v0.w;
            O[4] += pv * v1.x; O[5] += pv * v1.y; O[6] += pv * v1.z; O[7] += pv * v1.w;
        }
    }
    // ---- epilogue ----
    if (qo < nq) {
        float invl = 1.f / lS[qo];
        float* op = out + ((size_t)(b * NQ + q0 + qo)) * DM + h * DHEAD + dg * 8;
        #pragma unroll
        for (int d = 0; d < 8; d++) op[d] = O[d] * invl;
    }
}

// ---------------------------------------------------------------------------
// out = LN(res + x)*g + b ; optional mirror write into d_out (dtype per flag).
// ---------------------------------------------------------------------------
__global__ __launch_bounds__(256) void ln_kernel(const float* res,
        const float* __restrict__ x, const void* __restrict__ gw,
        const void* __restrict__ bw, float* out, void* __restrict__ oout,
        size_t obase, const float* __restrict__ flagp)
{
    const bool ef = flagp[0] > 0.5f;
    int row = blockIdx.x, d = threadIdx.x;
    size_t off = (size_t)row * DM + d;
    float v = res[off] + x[off];
    __shared__ float red[256];
    red[d] = v;
    __syncthreads();
    for (int st = 128; st > 0; st >>= 1) {
        if (d < st) red[d] += red[d + st];
        __syncthreads();
    }
    float mu = red[0] * (1.f / DM);
    __syncthreads();
    float dv = v - mu;
    red[d] = dv * dv;
    __syncthreads();
    for (int st = 128; st > 0; st >>= 1) {
        if (d < st) red[d] += red[d + st];
        __syncthreads();
    }
    float var = red[0] * (1.f / DM);
    float o = dv * rsqrtf(var + LN_EPS) * ldv(gw, d, 2, ef) + ldv(bw, d, 2, ef);
    out[off] = o;
    if (oout) {
        if (ef) ((float*)oout)[obase + off] = o;
        else    ((bf16*)oout)[obase + off] = __float2bfloat16(o);
    }
}

// ---------------------------------------------------------------------------
__global__ __launch_bounds__(256) void aw_softmax(float* __restrict__ aw)
{
    int i = blockIdx.x * 256 + threadIdx.x;
    if (i >= BQ * NHEADS) return;
    float* p = aw + (size_t)i * 16;
    float mx = -1e30f;
    #pragma unroll
    for (int j = 0; j < 16; j++) mx = fmaxf(mx, p[j]);
    float s = 0.f;
    #pragma unroll
    for (int j = 0; j < 16; j++) { float e = __expf(p[j] - mx); p[j] = e; s += e; }
    float inv = 1.f / s;
    #pragma unroll
    for (int j = 0; j < 16; j++) p[j] *= inv;
}

// ---------------------------------------------------------------------------
// MSDA sampling — unchanged from round 3
// ---------------------------------------------------------------------------
__global__ __launch_bounds__(256) void msda_sample(const bf16* __restrict__ value,
        const float* __restrict__ off, const float* __restrict__ aw,
        const void* __restrict__ refp, const void* __restrict__ vr,
        float* __restrict__ out, const float* __restrict__ flagp)
{
    const bool ef = flagp[0] > 0.5f;
    int bq = blockIdx.x; int b = bq / NQ;
    int tid = threadIdx.x; int h = tid >> 5, d = tid & 31;
    __shared__ float sOff[256];
    __shared__ float sAw[128];
    __shared__ float sref[2];
    __shared__ float svr[8];
    sOff[tid] = off[(size_t)bq * 256 + tid];
    if (tid < 128) sAw[tid] = aw[(size_t)bq * 128 + tid];
    if (tid < 2)   sref[tid] = ldv(refp, bq * 2 + tid, 2, ef);
    if (tid < 8)   svr[tid]  = ldv(vr, b * 8 + tid, 2, ef);
    __syncthreads();
    const bf16* vb = value + (size_t)b * NS * DM + h * DHEAD + d;
    const int HS[4] = {100, 50, 25, 13};
    const int ST[4] = {0, 10000, 12500, 13125};
    float acc = 0.f;
    #pragma unroll
    for (int lvl = 0; lvl < 4; lvl++) {
        int W_ = HS[lvl], H_ = HS[lvl], st = ST[lvl];
        float rx = sref[0] * svr[lvl*2 + 0] * (float)W_;
        float ry = sref[1] * svr[lvl*2 + 1] * (float)H_;
        #pragma unroll
        for (int p = 0; p < 4; p++) {
            int oi = h * 32 + lvl * 8 + p * 2;
            float x = fminf(fmaxf(rx + sOff[oi]     - 0.5f, -4.f), (float)W_ + 4.f);
            float y = fminf(fmaxf(ry + sOff[oi + 1] - 0.5f, -4.f), (float)H_ + 4.f);
            float x0f = floorf(x), y0f = floorf(y);
            float wx = x - x0f, wy = y - y0f;
            int x0 = (int)x0f, y0 = (int)y0f;
            int x1i = x0 + 1, y1i = y0 + 1;
            bool vx0 = (x0 >= 0) && (x0 < W_), vx1 = (x1i >= 0) && (x1i < W_);
            bool vy0 = (y0 >= 0) && (y0 < H_), vy1 = (y1i >= 0) && (y1i < H_);
            float g = 0.f;
            if (vy0) {
                int rowo = (st + y0 * W_) * DM;
                if (vx0) g += (1.f - wx) * (1.f - wy) * __bfloat162float(vb[rowo + x0  * DM]);
                if (vx1) g += wx         * (1.f - wy) * __bfloat162float(vb[rowo + x1i * DM]);
            }
            if (vy1) {
                int rowo = (st + y1i * W_) * DM;
                if (vx0) g += (1.f - wx) * wy * __bfloat162float(vb[rowo + x0  * DM]);
                if (vx1) g += wx         * wy * __bfloat162float(vb[rowo + x1i * DM]);
            }
            acc += g * sAw[h * 16 + lvl * 4 + p];
        }
    }
    out[(size_t)bq * DM + tid] = acc;
}

// ---------------------------------------------------------------------------
__global__ __launch_bounds__(256) void copy_refs(const void* __restrict__ refp,
        void* __restrict__ out, const float* __restrict__ flagp)
{
    const bool ef = flagp[0] > 0.5f;
    int i = blockIdx.x * 256 + threadIdx.x;
    if (i >= NLAY * BQ * 2) return;
    float v = ldv(refp, i % (BQ * 2), 2, ef);
    size_t oi = (size_t)NLAY * BQ * DM + i;
    if (ef) ((float*)out)[oi] = v;
    else    ((bf16*)out)[oi] = __float2bfloat16(v);
}

// ---------------------------------------------------------------------------
extern "C" void kernel_launch(void* const* d_in, const int* in_sizes, int n_in,
                              void* d_out, int out_size, void* d_ws, size_t ws_size,
                              hipStream_t stream)
{
    const void* tgt     = d_in[0];
    const void* refp    = d_in[1];
    const void* memory  = d_in[2];
    const void* vr      = d_in[5];
    const void* qp      = d_in[6];
    const void* sa_in_w = d_in[7];
    const void* sa_in_b = d_in[8];
    const void* sa_out_w= d_in[9];
    const void* sa_out_b= d_in[10];
    const void* n1_g    = d_in[11];
    const void* n1_b    = d_in[12];
    const void* n2_g    = d_in[13];
    const void* n2_b    = d_in[14];
    const void* n3_g    = d_in[15];
    const void* n3_b    = d_in[16];
    const void* vp_w    = d_in[17];
    const void* vp_b    = d_in[18];
    const void* so_w    = d_in[19];
    const void* so_b    = d_in[20];
    const void* aw_w    = d_in[21];
    const void* aw_b    = d_in[22];
    const void* op_w    = d_in[23];
    const void* op_b    = d_in[24];
    const void* ff1_w   = d_in[25];
    const void* ff1_b   = d_in[26];
    const void* ff2_w   = d_in[27];
    const void* ff2_b   = d_in[28];

    // ---- workspace layout ----
    char* w = (char*)d_ws;
    float* flagp  = (float*)w;  w += 256;
    bf16*  value  = (bf16*)w;   w += (size_t)NB * NS * DM * 2;   // 54.45 MB
    float* outbuf = (float*)w;  w += (size_t)BQ * DM * 4;
    float* x1samp = (float*)w;  w += (size_t)BQ * DM * 4;        // x1, later samp
    bf16*  bigb   = (bf16*)w;   w += (size_t)BQ * NFF * 2;       // qkv / ffn hidden
    float* attoff = (float*)w;  w += (size_t)BQ * DM * 4;        // attn, later offsets
    float* t2     = (float*)w;  w += (size_t)BQ * DM * 4;
    float* awb    = (float*)w;  w += (size_t)BQ * 128 * 4;

    const int gy = (BQ + 63) / 64;      // 113
    const int MV = NB * NS;             // 106352

    // 0) detect external dtype
    detect_dtype<<<1, 256, 0, stream>>>(tgt, flagp);

    // 1) value projection (layer-invariant)
    gemm_bias<<<dim3(DM/64, (MV + 63) / 64), 256, 0, stream>>>(
        memory, 2, vp_w, vp_b, value, 1, MV, DM, DM, 0, flagp);

    // 2) inter_refs output
    copy_refs<<<(NLAY * BQ * 2 + 255) / 256, 256, 0, stream>>>(refp, d_out, flagp);

    for (int l = 0; l < NLAY; l++) {
        // x1 = output + query_pos
        if (l == 0) add_qpos<<<BQ * DM / 256, 256, 0, stream>>>(tgt, 2, qp, x1samp, flagp);
        else        add_qpos<<<BQ * DM / 256, 256, 0, stream>>>(outbuf, 0, qp, x1samp, flagp);

        // self-attention
        gemm_bias<<<dim3(768/64, gy), 256, 0, stream>>>(
            x1samp, 0, sa_in_w, sa_in_b, bigb, 1, BQ, 768, DM, 0, flagp);
        mha_flash<<<dim3(15, NHEADS, NB), 256, 0, stream>>>(bigb, attoff);
        gemm_bias<<<dim3(DM/64, gy), 256, 0, stream>>>(
            attoff, 0, sa_out_w, sa_out_b, t2, 0, BQ, DM, DM, 0, flagp);
        ln_kernel<<<BQ, 256, 0, stream>>>(x1samp, t2, n1_g, n1_b, outbuf,
                                          nullptr, 0, flagp);

        // MSDA
        gemm_bias<<<dim3(DM/64, gy), 256, 0, stream>>>(
            outbuf, 0, so_w, so_b, attoff, 0, BQ, DM, DM, 0, flagp);
        gemm_bias<<<dim3(128/64, gy), 256, 0, stream>>>(
            outbuf, 0, aw_w, aw_b, awb, 0, BQ, 128, DM, 0, flagp);
        aw_softmax<<<(BQ * NHEADS + 255) / 256, 256, 0, stream>>>(awb);
        msda_sample<<<BQ, 256, 0, stream>>>(value, attoff, awb, refp, vr, x1samp, flagp);
        gemm_bias<<<dim3(DM/64, gy), 256, 0, stream>>>(
            x1samp, 0, op_w, op_b, t2, 0, BQ, DM, DM, 0, flagp);
        ln_kernel<<<BQ, 256, 0, stream>>>(outbuf, t2, n2_g, n2_b, outbuf,
                                          nullptr, 0, flagp);

        // FFN
        gemm_bias<<<dim3(NFF/64, gy), 256, 0, stream>>>(
            outbuf, 0, ff1_w, ff1_b, bigb, 1, BQ, NFF, DM, 1, flagp);
        gemm_bias<<<dim3(DM/64, gy), 256, 0, stream>>>(
            bigb, 1, ff2_w, ff2_b, t2, 0, BQ, DM, NFF, 0, flagp);
        ln_kernel<<<BQ, 256, 0, stream>>>(outbuf, t2, n3_g, n3_b, outbuf,
                                          d_out, (size_t)l * BQ * DM, flagp);
    }
}

// Round 5
// 2787.528 us; speedup vs baseline: 4.1240x; 2.0006x over previous
//
#include <hip/hip_runtime.h>
#include <hip/hip_bf16.h>

typedef __hip_bfloat16 bf16;
typedef __bf16 bf16x8 __attribute__((ext_vector_type(8)));
typedef float  f32x4  __attribute__((ext_vector_type(4)));

#define NB 8
#define NQ 900
#define DM 256
#define NHEADS 8
#define DHEAD 32
#define NFF 1024
#define NLAY 6
#define NS 13294
#define BQ (NB*NQ)            // 7200
#define LN_EPS 1e-5f
#define ATT_SCALE 0.17677669529663687f   // 1/sqrt(32)
#define SAK 40                // LDS row stride (bf16) for 64x32 tiles: 80B, 16B-aligned,
                              // stride-5 in 16B units -> balanced bank quads

__device__ __forceinline__ float bfd(const bf16* p, size_t i){ return __bfloat162float(p[i]); }

// mode: 0 = fp32 (internal), 1 = bf16 (internal), 2 = external (dtype per flag)
__device__ __forceinline__ float ldv(const void* p, size_t i, int mode, bool extF32)
{
    if (mode == 0) return ((const float*)p)[i];
    if (mode == 1) return bfd((const bf16*)p, i);
    return extF32 ? ((const float*)p)[i] : bfd((const bf16*)p, i);
}

// unpack 8 bf16 (16B) to floats
__device__ __forceinline__ void unpack8(uint4 u, float* t)
{
    t[0] = __uint_as_float((u.x & 0xffffu) << 16);
    t[1] = __uint_as_float(u.x & 0xffff0000u);
    t[2] = __uint_as_float((u.y & 0xffffu) << 16);
    t[3] = __uint_as_float(u.y & 0xffff0000u);
    t[4] = __uint_as_float((u.z & 0xffffu) << 16);
    t[5] = __uint_as_float(u.z & 0xffff0000u);
    t[6] = __uint_as_float((u.w & 0xffffu) << 16);
    t[7] = __uint_as_float(u.w & 0xffff0000u);
}

// ---------------------------------------------------------------------------
// dtype detector (inputs proved fp32; kept for robustness)
// ---------------------------------------------------------------------------
__global__ __launch_bounds__(256) void detect_dtype(const void* __restrict__ tgt,
        float* __restrict__ flag)
{
    __shared__ float red[256];
    int t = threadIdx.x;
    const unsigned short* u = (const unsigned short*)tgt;
    float m = 0.f;
    for (int i = t; i < 2048; i += 256) {
        unsigned int bits = ((unsigned int)u[i]) << 16;
        float v = fabsf(__uint_as_float(bits));
        if (!isfinite(v)) v = 1e30f;
        m = fmaxf(m, v);
    }
    red[t] = m;
    __syncthreads();
    for (int st = 128; st; st >>= 1) {
        if (t < st) red[t] = fmaxf(red[t], red[t + st]);
        __syncthreads();
    }
    if (t == 0) flag[0] = (red[0] > 1e8f) ? 1.f : 0.f;
}

// ---------------------------------------------------------------------------
// MFMA GEMM: C[M,N] = A[M,K] @ W[N,K]^T + bias[N]  (optional relu)
// 64x64 tile, 256 thr = 4 waves; wave w: rows [w*16,w*16+16) x 64 cols.
// BK=32, v_mfma_f32_16x16x32_bf16. N%64==0, K%32==0.
// a-frag: A[m=lane&15][k=quad*8+j]; b-frag: W[n=lane&15][k=quad*8+j];
// C/D: m=quad*4+reg, n=lane&15 (verified m89 mapping).
// ---------------------------------------------------------------------------
__global__ __launch_bounds__(256) void gemm_mfma(const void* __restrict__ A, int amode,
        const void* __restrict__ W, const void* __restrict__ bias,
        void* __restrict__ C, int cmode, int M, int N, int K, int relu,
        const float* __restrict__ flagp)
{
    const bool ef = flagp[0] > 0.5f;
    const bool a_bf16 = (amode == 1) || (amode == 2 && !ef);
    const bool w_bf16 = !ef;
    __shared__ __align__(16) bf16 As[64 * SAK];
    __shared__ __align__(16) bf16 Ws[64 * SAK];
    const int tid = threadIdx.x;
    const int m0 = blockIdx.y * 64, n0 = blockIdx.x * 64;
    const int w    = tid >> 6;       // wave id = m-tile
    const int lane = tid & 63;
    const int lm   = lane & 15;      // fragment row (m or n)
    const int lq   = lane >> 4;      // quad
    const int srow = tid >> 2;       // staging row 0..63
    const int sk   = (tid & 3) * 8;  // staging k-offset

    f32x4 acc[4] = {{0.f,0.f,0.f,0.f},{0.f,0.f,0.f,0.f},
                    {0.f,0.f,0.f,0.f},{0.f,0.f,0.f,0.f}};

    const int arow = m0 + srow;
    const bool avalid = arow < M;

    for (int k0 = 0; k0 < K; k0 += 32) {
        // ---- stage A (64x32 -> bf16) ----
        {
            bf16 tmp[8];
            if (avalid) {
                size_t base = (size_t)arow * K + k0 + sk;
                if (a_bf16) {
                    *(uint4*)tmp = *(const uint4*)((const bf16*)A + base);
                } else {
                    const float* ap = (const float*)A + base;
                    float4 f0 = *(const float4*)ap;
                    float4 f1 = *(const float4*)(ap + 4);
                    tmp[0] = __float2bfloat16(f0.x); tmp[1] = __float2bfloat16(f0.y);
                    tmp[2] = __float2bfloat16(f0.z); tmp[3] = __float2bfloat16(f0.w);
                    tmp[4] = __float2bfloat16(f1.x); tmp[5] = __float2bfloat16(f1.y);
                    tmp[6] = __float2bfloat16(f1.z); tmp[7] = __float2bfloat16(f1.w);
                }
            } else {
                #pragma unroll
                for (int i = 0; i < 8; i++) tmp[i] = __float2bfloat16(0.f);
            }
            *(uint4*)&As[srow * SAK + sk] = *(const uint4*)tmp;
        }
        // ---- stage W (64x32 -> bf16) ----
        {
            bf16 tmp[8];
            size_t base = (size_t)(n0 + srow) * K + k0 + sk;
            if (w_bf16) {
                *(uint4*)tmp = *(const uint4*)((const bf16*)W + base);
            } else {
                const float* wp = (const float*)W + base;
                float4 f0 = *(const float4*)wp;
                float4 f1 = *(const float4*)(wp + 4);
                tmp[0] = __float2bfloat16(f0.x); tmp[1] = __float2bfloat16(f0.y);
                tmp[2] = __float2bfloat16(f0.z); tmp[3] = __float2bfloat16(f0.w);
                tmp[4] = __float2bfloat16(f1.x); tmp[5] = __float2bfloat16(f1.y);
                tmp[6] = __float2bfloat16(f1.z); tmp[7] = __float2bfloat16(f1.w);
            }
            *(uint4*)&Ws[srow * SAK + sk] = *(const uint4*)tmp;
        }
        __syncthreads();
        // ---- fragments + MFMA ----
        bf16x8 af = *(const bf16x8*)&As[(w * 16 + lm) * SAK + lq * 8];
        #pragma unroll
        for (int nt = 0; nt < 4; nt++) {
            bf16x8 bfr = *(const bf16x8*)&Ws[(nt * 16 + lm) * SAK + lq * 8];
            acc[nt] = __builtin_amdgcn_mfma_f32_16x16x32_bf16(af, bfr, acc[nt], 0, 0, 0);
        }
        __syncthreads();
    }

    // ---- epilogue ----
    #pragma unroll
    for (int nt = 0; nt < 4; nt++) {
        int n = n0 + nt * 16 + lm;
        float bv = ldv(bias, n, 2, ef);
        #pragma unroll
        for (int r = 0; r < 4; r++) {
            int m = m0 + w * 16 + lq * 4 + r;
            if (m >= M) continue;
            float v = acc[nt][r] + bv;
            if (relu) v = fmaxf(v, 0.f);
            size_t ci = (size_t)m * N + n;
            if (cmode == 0) ((float*)C)[ci] = v;
            else            ((bf16*)C)[ci] = __float2bfloat16(v);
        }
    }
}

// ---------------------------------------------------------------------------
__global__ __launch_bounds__(256) void add_qpos(const void* __restrict__ a, int amode,
        const void* __restrict__ qp, float* __restrict__ o, const float* __restrict__ flagp)
{
    const bool ef = flagp[0] > 0.5f;
    int i = blockIdx.x * 256 + threadIdx.x;
    o[i] = ldv(a, i, amode, ef) + ldv(qp, i, 2, ef);
}

// ---------------------------------------------------------------------------
// Flash MHA — unchanged from round 4
// ---------------------------------------------------------------------------
__global__ __launch_bounds__(256) void mha_flash(const bf16* __restrict__ qkv,
        float* __restrict__ out)
{
    const int qt = blockIdx.x, h = blockIdx.y, b = blockIdx.z;
    const int q0 = qt * 64;
    const int nq = min(64, NQ - q0);
    const int tid = threadIdx.x;
    const int qi = tid & 63;
    const int kg = tid >> 6;
    const int qo = tid >> 2;
    const int dg = tid & 3;

    __shared__ __align__(16) float Ks[64][36];
    __shared__ __align__(16) float Vs[64][36];
    __shared__ float Ps[64][65];
    __shared__ float sred[4][64];
    __shared__ float mS[64], lS[64], aS[64];

    const bf16* base = qkv + (size_t)b * NQ * 768;
    const int row = tid >> 2, c0 = (tid & 3) * 8;

    {
        float t[8];
        if (q0 + row < NQ) {
            uint4 u = *(const uint4*)(base + (size_t)(q0 + row) * 768 + h * DHEAD + c0);
            unpack8(u, t);
        } else {
            #pragma unroll
            for (int i = 0; i < 8; i++) t[i] = 0.f;
        }
        #pragma unroll
        for (int i = 0; i < 8; i++) Ks[row][c0 + i] = t[i] * ATT_SCALE;
    }
    if (tid < 64) { mS[tid] = -1e30f; lS[tid] = 0.f; }
    __syncthreads();
    float qreg[32];
    #pragma unroll
    for (int d4 = 0; d4 < 8; d4++) {
        float4 v = *(const float4*)&Ks[qi][d4 * 4];
        qreg[d4*4+0] = v.x; qreg[d4*4+1] = v.y; qreg[d4*4+2] = v.z; qreg[d4*4+3] = v.w;
    }
    float O[8] = {0.f,0.f,0.f,0.f,0.f,0.f,0.f,0.f};

    for (int k0 = 0; k0 < NQ; k0 += 64) {
        __syncthreads();
        {
            float tk[8], tv[8];
            if (k0 + row < NQ) {
                const bf16* rp = base + (size_t)(k0 + row) * 768 + h * DHEAD + c0;
                uint4 uk = *(const uint4*)(rp + 256);
                uint4 uv = *(const uint4*)(rp + 512);
                unpack8(uk, tk); unpack8(uv, tv);
            } else {
                #pragma unroll
                for (int i = 0; i < 8; i++) { tk[i] = 0.f; tv[i] = 0.f; }
            }
            #pragma unroll
            for (int i = 0; i < 8; i++) { Ks[row][c0+i] = tk[i]; Vs[row][c0+i] = tv[i]; }
        }
        __syncthreads();
        const int kvalid = NQ - k0;
        float s[16];
        #pragma unroll
        for (int j = 0; j < 16; j++) {
            int kj = kg * 16 + j;
            float acc = 0.f;
            #pragma unroll
            for (int d4 = 0; d4 < 8; d4++) {
                float4 kv = *(const float4*)&Ks[kj][d4 * 4];
                acc += qreg[d4*4+0]*kv.x + qreg[d4*4+1]*kv.y
                     + qreg[d4*4+2]*kv.z + qreg[d4*4+3]*kv.w;
            }
            s[j] = (kj < kvalid) ? acc : -1e30f;
        }
        float tmax = s[0];
        #pragma unroll
        for (int j = 1; j < 16; j++) tmax = fmaxf(tmax, s[j]);
        sred[kg][qi] = tmax;
        __syncthreads();
        if (tid < 64) {
            float tm = fmaxf(fmaxf(sred[0][tid], sred[1][tid]),
                             fmaxf(sred[2][tid], sred[3][tid]));
            float mnew = fmaxf(mS[tid], tm);
            aS[tid] = __expf(mS[tid] - mnew);
            mS[tid] = mnew;
        }
        __syncthreads();
        float mq = mS[qi];
        float psum = 0.f;
        #pragma unroll
        for (int j = 0; j < 16; j++) {
            float p = __expf(s[j] - mq);
            Ps[qi][kg * 16 + j] = p;
            psum += p;
        }
        sred[kg][qi] = psum;
        __syncthreads();
        if (tid < 64)
            lS[tid] = lS[tid] * aS[tid]
                    + sred[0][tid] + sred[1][tid] + sred[2][tid] + sred[3][tid];
        float alpha = aS[qo];
        #pragma unroll
        for (int d = 0; d < 8; d++) O[d] *= alpha;
        #pragma unroll 4
        for (int k = 0; k < 64; k++) {
            float pv = Ps[qo][k];
            float4 v0 = *(const float4*)&Vs[k][dg * 8];
            float4 v1 = *(const float4*)&Vs[k][dg * 8 + 4];
            O[0] += pv * v0.x; O[1] += pv * v0.y; O[2] += pv * v0.z; O[3] += pv * v0.w;
            O[4] += pv * v1.x; O[5] += pv * v1.y; O[6] += pv * v1.z; O[7] += pv * v1.w;
        }
    }
    if (qo < nq) {
        float invl = 1.f / lS[qo];
        float* op = out + ((size_t)(b * NQ + q0 + qo)) * DM + h * DHEAD + dg * 8;
        #pragma unroll
        for (int d = 0; d < 8; d++) op[d] = O[d] * invl;
    }
}

// ---------------------------------------------------------------------------
__global__ __launch_bounds__(256) void ln_kernel(const float* res,
        const float* __restrict__ x, const void* __restrict__ gw,
        const void* __restrict__ bw, float* out, void* __restrict__ oout,
        size_t obase, const float* __restrict__ flagp)
{
    const bool ef = flagp[0] > 0.5f;
    int row = blockIdx.x, d = threadIdx.x;
    size_t off = (size_t)row * DM + d;
    float v = res[off] + x[off];
    __shared__ float red[256];
    red[d] = v;
    __syncthreads();
    for (int st = 128; st > 0; st >>= 1) {
        if (d < st) red[d] += red[d + st];
        __syncthreads();
    }
    float mu = red[0] * (1.f / DM);
    __syncthreads();
    float dv = v - mu;
    red[d] = dv * dv;
    __syncthreads();
    for (int st = 128; st > 0; st >>= 1) {
        if (d < st) red[d] += red[d + st];
        __syncthreads();
    }
    float var = red[0] * (1.f / DM);
    float o = dv * rsqrtf(var + LN_EPS) * ldv(gw, d, 2, ef) + ldv(bw, d, 2, ef);
    out[off] = o;
    if (oout) {
        if (ef) ((float*)oout)[obase + off] = o;
        else    ((bf16*)oout)[obase + off] = __float2bfloat16(o);
    }
}

// ---------------------------------------------------------------------------
__global__ __launch_bounds__(256) void aw_softmax(float* __restrict__ aw)
{
    int i = blockIdx.x * 256 + threadIdx.x;
    if (i >= BQ * NHEADS) return;
    float* p = aw + (size_t)i * 16;
    float mx = -1e30f;
    #pragma unroll
    for (int j = 0; j < 16; j++) mx = fmaxf(mx, p[j]);
    float s = 0.f;
    #pragma unroll
    for (int j = 0; j < 16; j++) { float e = __expf(p[j] - mx); p[j] = e; s += e; }
    float inv = 1.f / s;
    #pragma unroll
    for (int j = 0; j < 16; j++) p[j] *= inv;
}

// ---------------------------------------------------------------------------
__global__ __launch_bounds__(256) void msda_sample(const bf16* __restrict__ value,
        const float* __restrict__ off, const float* __restrict__ aw,
        const void* __restrict__ refp, const void* __restrict__ vr,
        float* __restrict__ out, const float* __restrict__ flagp)
{
    const bool ef = flagp[0] > 0.5f;
    int bq = blockIdx.x; int b = bq / NQ;
    int tid = threadIdx.x; int h = tid >> 5, d = tid & 31;
    __shared__ float sOff[256];
    __shared__ float sAw[128];
    __shared__ float sref[2];
    __shared__ float svr[8];
    sOff[tid] = off[(size_t)bq * 256 + tid];
    if (tid < 128) sAw[tid] = aw[(size_t)bq * 128 + tid];
    if (tid < 2)   sref[tid] = ldv(refp, bq * 2 + tid, 2, ef);
    if (tid < 8)   svr[tid]  = ldv(vr, b * 8 + tid, 2, ef);
    __syncthreads();
    const bf16* vb = value + (size_t)b * NS * DM + h * DHEAD + d;
    const int HS[4] = {100, 50, 25, 13};
    const int ST[4] = {0, 10000, 12500, 13125};
    float acc = 0.f;
    #pragma unroll
    for (int lvl = 0; lvl < 4; lvl++) {
        int W_ = HS[lvl], H_ = HS[lvl], st = ST[lvl];
        float rx = sref[0] * svr[lvl*2 + 0] * (float)W_;
        float ry = sref[1] * svr[lvl*2 + 1] * (float)H_;
        #pragma unroll
        for (int p = 0; p < 4; p++) {
            int oi = h * 32 + lvl * 8 + p * 2;
            float x = fminf(fmaxf(rx + sOff[oi]     - 0.5f, -4.f), (float)W_ + 4.f);
            float y = fminf(fmaxf(ry + sOff[oi + 1] - 0.5f, -4.f), (float)H_ + 4.f);
            float x0f = floorf(x), y0f = floorf(y);
            float wx = x - x0f, wy = y - y0f;
            int x0 = (int)x0f, y0 = (int)y0f;
            int x1i = x0 + 1, y1i = y0 + 1;
            bool vx0 = (x0 >= 0) && (x0 < W_), vx1 = (x1i >= 0) && (x1i < W_);
            bool vy0 = (y0 >= 0) && (y0 < H_), vy1 = (y1i >= 0) && (y1i < H_);
            float g = 0.f;
            if (vy0) {
                int rowo = (st + y0 * W_) * DM;
                if (vx0) g += (1.f - wx) * (1.f - wy) * __bfloat162float(vb[rowo + x0  * DM]);
                if (vx1) g += wx         * (1.f - wy) * __bfloat162float(vb[rowo + x1i * DM]);
            }
            if (vy1) {
                int rowo = (st + y1i * W_) * DM;
                if (vx0) g += (1.f - wx) * wy * __bfloat162float(vb[rowo + x0  * DM]);
                if (vx1) g += wx         * wy * __bfloat162float(vb[rowo + x1i * DM]);
            }
            acc += g * sAw[h * 16 + lvl * 4 + p];
        }
    }
    out[(size_t)bq * DM + tid] = acc;
}

// ---------------------------------------------------------------------------
__global__ __launch_bounds__(256) void copy_refs(const void* __restrict__ refp,
        void* __restrict__ out, const float* __restrict__ flagp)
{
    const bool ef = flagp[0] > 0.5f;
    int i = blockIdx.x * 256 + threadIdx.x;
    if (i >= NLAY * BQ * 2) return;
    float v = ldv(refp, i % (BQ * 2), 2, ef);
    size_t oi = (size_t)NLAY * BQ * DM + i;
    if (ef) ((float*)out)[oi] = v;
    else    ((bf16*)out)[oi] = __float2bfloat16(v);
}

// ---------------------------------------------------------------------------
extern "C" void kernel_launch(void* const* d_in, const int* in_sizes, int n_in,
                              void* d_out, int out_size, void* d_ws, size_t ws_size,
                              hipStream_t stream)
{
    const void* tgt     = d_in[0];
    const void* refp    = d_in[1];
    const void* memory  = d_in[2];
    const void* vr      = d_in[5];
    const void* qp      = d_in[6];
    const void* sa_in_w = d_in[7];
    const void* sa_in_b = d_in[8];
    const void* sa_out_w= d_in[9];
    const void* sa_out_b= d_in[10];
    const void* n1_g    = d_in[11];
    const void* n1_b    = d_in[12];
    const void* n2_g    = d_in[13];
    const void* n2_b    = d_in[14];
    const void* n3_g    = d_in[15];
    const void* n3_b    = d_in[16];
    const void* vp_w    = d_in[17];
    const void* vp_b    = d_in[18];
    const void* so_w    = d_in[19];
    const void* so_b    = d_in[20];
    const void* aw_w    = d_in[21];
    const void* aw_b    = d_in[22];
    const void* op_w    = d_in[23];
    const void* op_b    = d_in[24];
    const void* ff1_w   = d_in[25];
    const void* ff1_b   = d_in[26];
    const void* ff2_w   = d_in[27];
    const void* ff2_b   = d_in[28];

    // ---- workspace layout ----
    char* w = (char*)d_ws;
    float* flagp  = (float*)w;  w += 256;
    bf16*  value  = (bf16*)w;   w += (size_t)NB * NS * DM * 2;   // 54.45 MB
    float* outbuf = (float*)w;  w += (size_t)BQ * DM * 4;
    float* x1samp = (float*)w;  w += (size_t)BQ * DM * 4;        // x1, later samp
    bf16*  bigb   = (bf16*)w;   w += (size_t)BQ * NFF * 2;       // qkv / ffn hidden
    float* attoff = (float*)w;  w += (size_t)BQ * DM * 4;        // attn, later offsets
    float* t2     = (float*)w;  w += (size_t)BQ * DM * 4;
    float* awb    = (float*)w;  w += (size_t)BQ * 128 * 4;

    const int gy = (BQ + 63) / 64;      // 113
    const int MV = NB * NS;             // 106352

    // 0) detect external dtype
    detect_dtype<<<1, 256, 0, stream>>>(tgt, flagp);

    // 1) value projection (layer-invariant)
    gemm_mfma<<<dim3(DM/64, (MV + 63) / 64), 256, 0, stream>>>(
        memory, 2, vp_w, vp_b, value, 1, MV, DM, DM, 0, flagp);

    // 2) inter_refs output
    copy_refs<<<(NLAY * BQ * 2 + 255) / 256, 256, 0, stream>>>(refp, d_out, flagp);

    for (int l = 0; l < NLAY; l++) {
        // x1 = output + query_pos
        if (l == 0) add_qpos<<<BQ * DM / 256, 256, 0, stream>>>(tgt, 2, qp, x1samp, flagp);
        else        add_qpos<<<BQ * DM / 256, 256, 0, stream>>>(outbuf, 0, qp, x1samp, flagp);

        // self-attention
        gemm_mfma<<<dim3(768/64, gy), 256, 0, stream>>>(
            x1samp, 0, sa_in_w, sa_in_b, bigb, 1, BQ, 768, DM, 0, flagp);
        mha_flash<<<dim3(15, NHEADS, NB), 256, 0, stream>>>(bigb, attoff);
        gemm_mfma<<<dim3(DM/64, gy), 256, 0, stream>>>(
            attoff, 0, sa_out_w, sa_out_b, t2, 0, BQ, DM, DM, 0, flagp);
        ln_kernel<<<BQ, 256, 0, stream>>>(x1samp, t2, n1_g, n1_b, outbuf,
                                          nullptr, 0, flagp);

        // MSDA
        gemm_mfma<<<dim3(DM/64, gy), 256, 0, stream>>>(
            outbuf, 0, so_w, so_b, attoff, 0, BQ, DM, DM, 0, flagp);
        gemm_mfma<<<dim3(128/64, gy), 256, 0, stream>>>(
            outbuf, 0, aw_w, aw_b, awb, 0, BQ, 128, DM, 0, flagp);
        aw_softmax<<<(BQ * NHEADS + 255) / 256, 256, 0, stream>>>(awb);
        msda_sample<<<BQ, 256, 0, stream>>>(value, attoff, awb, refp, vr, x1samp, flagp);
        gemm_mfma<<<dim3(DM/64, gy), 256, 0, stream>>>(
            x1samp, 0, op_w, op_b, t2, 0, BQ, DM, DM, 0, flagp);
        ln_kernel<<<BQ, 256, 0, stream>>>(outbuf, t2, n2_g, n2_b, outbuf,
                                          nullptr, 0, flagp);

        // FFN
        gemm_mfma<<<dim3(NFF/64, gy), 256, 0, stream>>>(
            outbuf, 0, ff1_w, ff1_b, bigb, 1, BQ, NFF, DM, 1, flagp);
        gemm_mfma<<<dim3(DM/64, gy), 256, 0, stream>>>(
            bigb, 1, ff2_w, ff2_b, t2, 0, BQ, DM, NFF, 0, flagp);
        ln_kernel<<<BQ, 256, 0, stream>>>(outbuf, t2, n3_g, n3_b, outbuf,
                                          d_out, (size_t)l * BQ * DM, flagp);
    }
}

// Round 6
// 2007.055 us; speedup vs baseline: 5.7277x; 1.3889x over previous
//
#include <hip/hip_runtime.h>
#include <hip/hip_bf16.h>

typedef __hip_bfloat16 bf16;
typedef __bf16 bf16x8 __attribute__((ext_vector_type(8)));
typedef float  f32x4  __attribute__((ext_vector_type(4)));

#define NB 8
#define NQ 900
#define DM 256
#define NHEADS 8
#define DHEAD 32
#define NFF 1024
#define NLAY 6
#define NS 13294
#define BQ (NB*NQ)            // 7200
#define LN_EPS 1e-5f
#define ATT_SCALE 0.17677669529663687f   // 1/sqrt(32)
#define SAK 40                // LDS row stride (bf16): 80B, stride-5 in 16B units

__device__ __forceinline__ float bfd(const bf16* p, size_t i){ return __bfloat162float(p[i]); }

// mode: 0 = fp32 (internal), 1 = bf16 (internal), 2 = external (dtype per flag)
__device__ __forceinline__ float ldv(const void* p, size_t i, int mode, bool extF32)
{
    if (mode == 0) return ((const float*)p)[i];
    if (mode == 1) return bfd((const bf16*)p, i);
    return extF32 ? ((const float*)p)[i] : bfd((const bf16*)p, i);
}

// unpack 8 bf16 (16B) to floats
__device__ __forceinline__ void unpack8(uint4 u, float* t)
{
    t[0] = __uint_as_float((u.x & 0xffffu) << 16);
    t[1] = __uint_as_float(u.x & 0xffff0000u);
    t[2] = __uint_as_float((u.y & 0xffffu) << 16);
    t[3] = __uint_as_float(u.y & 0xffff0000u);
    t[4] = __uint_as_float((u.z & 0xffffu) << 16);
    t[5] = __uint_as_float(u.z & 0xffff0000u);
    t[6] = __uint_as_float((u.w & 0xffffu) << 16);
    t[7] = __uint_as_float(u.w & 0xffff0000u);
}

// ---------------------------------------------------------------------------
// dtype detector (inputs proved fp32; kept for robustness)
// ---------------------------------------------------------------------------
__global__ __launch_bounds__(256) void detect_dtype(const void* __restrict__ tgt,
        float* __restrict__ flag)
{
    __shared__ float red[256];
    int t = threadIdx.x;
    const unsigned short* u = (const unsigned short*)tgt;
    float m = 0.f;
    for (int i = t; i < 2048; i += 256) {
        unsigned int bits = ((unsigned int)u[i]) << 16;
        float v = fabsf(__uint_as_float(bits));
        if (!isfinite(v)) v = 1e30f;
        m = fmaxf(m, v);
    }
    red[t] = m;
    __syncthreads();
    for (int st = 128; st; st >>= 1) {
        if (t < st) red[t] = fmaxf(red[t], red[t + st]);
        __syncthreads();
    }
    if (t == 0) flag[0] = (red[0] > 1e8f) ? 1.f : 0.f;
}

// ---------------------------------------------------------------------------
// MFMA GEMM — unchanged from round 5
// ---------------------------------------------------------------------------
__global__ __launch_bounds__(256) void gemm_mfma(const void* __restrict__ A, int amode,
        const void* __restrict__ W, const void* __restrict__ bias,
        void* __restrict__ C, int cmode, int M, int N, int K, int relu,
        const float* __restrict__ flagp)
{
    const bool ef = flagp[0] > 0.5f;
    const bool a_bf16 = (amode == 1) || (amode == 2 && !ef);
    const bool w_bf16 = !ef;
    __shared__ __align__(16) bf16 As[64 * SAK];
    __shared__ __align__(16) bf16 Ws[64 * SAK];
    const int tid = threadIdx.x;
    const int m0 = blockIdx.y * 64, n0 = blockIdx.x * 64;
    const int w    = tid >> 6;
    const int lane = tid & 63;
    const int lm   = lane & 15;
    const int lq   = lane >> 4;
    const int srow = tid >> 2;
    const int sk   = (tid & 3) * 8;

    f32x4 acc[4] = {{0.f,0.f,0.f,0.f},{0.f,0.f,0.f,0.f},
                    {0.f,0.f,0.f,0.f},{0.f,0.f,0.f,0.f}};

    const int arow = m0 + srow;
    const bool avalid = arow < M;

    for (int k0 = 0; k0 < K; k0 += 32) {
        {
            bf16 tmp[8];
            if (avalid) {
                size_t base = (size_t)arow * K + k0 + sk;
                if (a_bf16) {
                    *(uint4*)tmp = *(const uint4*)((const bf16*)A + base);
                } else {
                    const float* ap = (const float*)A + base;
                    float4 f0 = *(const float4*)ap;
                    float4 f1 = *(const float4*)(ap + 4);
                    tmp[0] = __float2bfloat16(f0.x); tmp[1] = __float2bfloat16(f0.y);
                    tmp[2] = __float2bfloat16(f0.z); tmp[3] = __float2bfloat16(f0.w);
                    tmp[4] = __float2bfloat16(f1.x); tmp[5] = __float2bfloat16(f1.y);
                    tmp[6] = __float2bfloat16(f1.z); tmp[7] = __float2bfloat16(f1.w);
                }
            } else {
                #pragma unroll
                for (int i = 0; i < 8; i++) tmp[i] = __float2bfloat16(0.f);
            }
            *(uint4*)&As[srow * SAK + sk] = *(const uint4*)tmp;
        }
        {
            bf16 tmp[8];
            size_t base = (size_t)(n0 + srow) * K + k0 + sk;
            if (w_bf16) {
                *(uint4*)tmp = *(const uint4*)((const bf16*)W + base);
            } else {
                const float* wp = (const float*)W + base;
                float4 f0 = *(const float4*)wp;
                float4 f1 = *(const float4*)(wp + 4);
                tmp[0] = __float2bfloat16(f0.x); tmp[1] = __float2bfloat16(f0.y);
                tmp[2] = __float2bfloat16(f0.z); tmp[3] = __float2bfloat16(f0.w);
                tmp[4] = __float2bfloat16(f1.x); tmp[5] = __float2bfloat16(f1.y);
                tmp[6] = __float2bfloat16(f1.z); tmp[7] = __float2bfloat16(f1.w);
            }
            *(uint4*)&Ws[srow * SAK + sk] = *(const uint4*)tmp;
        }
        __syncthreads();
        bf16x8 af = *(const bf16x8*)&As[(w * 16 + lm) * SAK + lq * 8];
        #pragma unroll
        for (int nt = 0; nt < 4; nt++) {
            bf16x8 bfr = *(const bf16x8*)&Ws[(nt * 16 + lm) * SAK + lq * 8];
            acc[nt] = __builtin_amdgcn_mfma_f32_16x16x32_bf16(af, bfr, acc[nt], 0, 0, 0);
        }
        __syncthreads();
    }

    #pragma unroll
    for (int nt = 0; nt < 4; nt++) {
        int n = n0 + nt * 16 + lm;
        float bv = ldv(bias, n, 2, ef);
        #pragma unroll
        for (int r = 0; r < 4; r++) {
            int m = m0 + w * 16 + lq * 4 + r;
            if (m >= M) continue;
            float v = acc[nt][r] + bv;
            if (relu) v = fmaxf(v, 0.f);
            size_t ci = (size_t)m * N + n;
            if (cmode == 0) ((float*)C)[ci] = v;
            else            ((bf16*)C)[ci] = __float2bfloat16(v);
        }
    }
}

// ---------------------------------------------------------------------------
__global__ __launch_bounds__(256) void add_qpos(const void* __restrict__ a, int amode,
        const void* __restrict__ qp, float* __restrict__ o, const float* __restrict__ flagp)
{
    const bool ef = flagp[0] > 0.5f;
    int i = blockIdx.x * 256 + threadIdx.x;
    o[i] = ldv(a, i, amode, ef) + ldv(qp, i, 2, ef);
}

// ---------------------------------------------------------------------------
// MFMA flash MHA. grid (15 qtiles, 8 h, 8 b), 256 thr = 4 waves.
// Computes S^T = K.Q^T so that C-layout puts one query per lane-column:
// softmax is in-lane over 16 regs + 2 shfl_xor across quads.
// P^T stored bf16 in LDS (stride 66: conflict-free column access);
// V staged transposed (Vt[32][66]); PV computes O^T = V^T.P via MFMA.
// m/l/alpha are per-lane scalars (lane <-> query).
// ---------------------------------------------------------------------------
__global__ __launch_bounds__(256) void mha_mfma(const bf16* __restrict__ qkv,
        float* __restrict__ out)
{
    const int qt = blockIdx.x, h = blockIdx.y, b = blockIdx.z;
    const int q0 = qt * 64;
    const int tid = threadIdx.x;
    const int w = tid >> 6, lane = tid & 63;
    const int lm = lane & 15, lq = lane >> 4;
    const int srow = tid >> 2, sc = (tid & 3) * 8;

    __shared__ __align__(16) bf16 Qs[64][SAK];
    __shared__ __align__(16) bf16 Ks[64][SAK];
    __shared__ __align__(16) bf16 Vt[32][66];
    __shared__ __align__(16) bf16 Pt[64][66];

    const bf16* base = qkv + (size_t)b * NQ * 768;

    // ---- stage Q (pre-scaled) ----
    {
        bf16 tmp[8];
        if (q0 + srow < NQ) {
            uint4 u = *(const uint4*)(base + (size_t)(q0 + srow) * 768 + h * DHEAD + sc);
            float t[8]; unpack8(u, t);
            #pragma unroll
            for (int i = 0; i < 8; i++) tmp[i] = __float2bfloat16(t[i] * ATT_SCALE);
        } else {
            #pragma unroll
            for (int i = 0; i < 8; i++) tmp[i] = __float2bfloat16(0.f);
        }
        *(uint4*)&Qs[srow][sc] = *(const uint4*)tmp;
    }
    __syncthreads();
    const bf16x8 qf = *(const bf16x8*)&Qs[w * 16 + lm][lq * 8];   // this lane's query row

    f32x4 O[2] = {{0.f,0.f,0.f,0.f},{0.f,0.f,0.f,0.f}};          // O^T: d rows, q col
    float mrow = -1e30f, lrow = 0.f;                              // for q = q0+w*16+lm

    for (int k0 = 0; k0 < NQ; k0 += 64) {
        __syncthreads();
        // ---- stage K tile + transposed V tile ----
        {
            uint4 uk = {0u,0u,0u,0u}, uv = {0u,0u,0u,0u};
            if (k0 + srow < NQ) {
                const bf16* rp = base + (size_t)(k0 + srow) * 768 + h * DHEAD + sc;
                uk = *(const uint4*)(rp + 256);
                uv = *(const uint4*)(rp + 512);
            }
            *(uint4*)&Ks[srow][sc] = uk;
            const bf16* vv = (const bf16*)&uv;
            #pragma unroll
            for (int i = 0; i < 8; i++) Vt[sc + i][srow] = vv[i];
        }
        __syncthreads();

        // ---- S^T = K.Q^T : 4 MFMAs (kv tiles), col = this lane's query ----
        float sv[16];
        #pragma unroll
        for (int mt = 0; mt < 4; mt++) {
            bf16x8 kf = *(const bf16x8*)&Ks[mt * 16 + lm][lq * 8];
            f32x4 d = __builtin_amdgcn_mfma_f32_16x16x32_bf16(kf, qf,
                        (f32x4){0.f,0.f,0.f,0.f}, 0, 0, 0);
            sv[mt*4+0] = d[0]; sv[mt*4+1] = d[1]; sv[mt*4+2] = d[2]; sv[mt*4+3] = d[3];
        }
        // mask invalid keys
        #pragma unroll
        for (int mt = 0; mt < 4; mt++)
            #pragma unroll
            for (int r = 0; r < 4; r++)
                if (k0 + mt * 16 + lq * 4 + r >= NQ) sv[mt*4+r] = -1e30f;

        // ---- online softmax (in-lane + 2 cross-quad shuffles) ----
        float tmax = sv[0];
        #pragma unroll
        for (int j = 1; j < 16; j++) tmax = fmaxf(tmax, sv[j]);
        tmax = fmaxf(tmax, __shfl_xor(tmax, 16, 64));
        tmax = fmaxf(tmax, __shfl_xor(tmax, 32, 64));
        float mnew = fmaxf(mrow, tmax);
        float alpha = __expf(mrow - mnew);
        mrow = mnew;
        float psum = 0.f;
        #pragma unroll
        for (int j = 0; j < 16; j++) {
            float p = __expf(sv[j] - mnew);
            sv[j] = p; psum += p;
        }
        psum += __shfl_xor(psum, 16, 64);
        psum += __shfl_xor(psum, 32, 64);
        lrow = lrow * alpha + psum;

        // ---- write P^T (bf16) ----
        #pragma unroll
        for (int mt = 0; mt < 4; mt++)
            #pragma unroll
            for (int r = 0; r < 4; r++)
                Pt[mt * 16 + lq * 4 + r][w * 16 + lm] = __float2bfloat16(sv[mt*4+r]);

        // ---- rescale O, then O^T += V^T.P (4 MFMAs) ----
        #pragma unroll
        for (int mt = 0; mt < 2; mt++)
            #pragma unroll
            for (int r = 0; r < 4; r++) O[mt][r] *= alpha;
        #pragma unroll
        for (int ks = 0; ks < 2; ks++) {
            union { bf16 a[8]; bf16x8 v; } pf;
            #pragma unroll
            for (int j = 0; j < 8; j++)
                pf.a[j] = Pt[ks * 32 + lq * 8 + j][w * 16 + lm];
            #pragma unroll
            for (int mt = 0; mt < 2; mt++) {
                bf16x8 vf = *(const bf16x8*)&Vt[mt * 16 + lm][ks * 32 + lq * 8];
                O[mt] = __builtin_amdgcn_mfma_f32_16x16x32_bf16(vf, pf.v, O[mt], 0, 0, 0);
            }
        }
    }

    // ---- epilogue: lane owns query q0+w*16+lm, dims d = mt*16+lq*4+r ----
    int q = q0 + w * 16 + lm;
    if (q < NQ) {
        float invl = 1.f / lrow;
        float* op = out + ((size_t)(b * NQ + q)) * DM + h * DHEAD;
        #pragma unroll
        for (int mt = 0; mt < 2; mt++)
            #pragma unroll
            for (int r = 0; r < 4; r++)
                op[mt * 16 + lq * 4 + r] = O[mt][r] * invl;
    }
}

// ---------------------------------------------------------------------------
__global__ __launch_bounds__(256) void ln_kernel(const float* res,
        const float* __restrict__ x, const void* __restrict__ gw,
        const void* __restrict__ bw, float* out, void* __restrict__ oout,
        size_t obase, const float* __restrict__ flagp)
{
    const bool ef = flagp[0] > 0.5f;
    int row = blockIdx.x, d = threadIdx.x;
    size_t off = (size_t)row * DM + d;
    float v = res[off] + x[off];
    __shared__ float red[256];
    red[d] = v;
    __syncthreads();
    for (int st = 128; st > 0; st >>= 1) {
        if (d < st) red[d] += red[d + st];
        __syncthreads();
    }
    float mu = red[0] * (1.f / DM);
    __syncthreads();
    float dv = v - mu;
    red[d] = dv * dv;
    __syncthreads();
    for (int st = 128; st > 0; st >>= 1) {
        if (d < st) red[d] += red[d + st];
        __syncthreads();
    }
    float var = red[0] * (1.f / DM);
    float o = dv * rsqrtf(var + LN_EPS) * ldv(gw, d, 2, ef) + ldv(bw, d, 2, ef);
    out[off] = o;
    if (oout) {
        if (ef) ((float*)oout)[obase + off] = o;
        else    ((bf16*)oout)[obase + off] = __float2bfloat16(o);
    }
}

// ---------------------------------------------------------------------------
__global__ __launch_bounds__(256) void aw_softmax(float* __restrict__ aw)
{
    int i = blockIdx.x * 256 + threadIdx.x;
    if (i >= BQ * NHEADS) return;
    float* p = aw + (size_t)i * 16;
    float mx = -1e30f;
    #pragma unroll
    for (int j = 0; j < 16; j++) mx = fmaxf(mx, p[j]);
    float s = 0.f;
    #pragma unroll
    for (int j = 0; j < 16; j++) { float e = __expf(p[j] - mx); p[j] = e; s += e; }
    float inv = 1.f / s;
    #pragma unroll
    for (int j = 0; j < 16; j++) p[j] *= inv;
}

// ---------------------------------------------------------------------------
__global__ __launch_bounds__(256) void msda_sample(const bf16* __restrict__ value,
        const float* __restrict__ off, const float* __restrict__ aw,
        const void* __restrict__ refp, const void* __restrict__ vr,
        float* __restrict__ out, const float* __restrict__ flagp)
{
    const bool ef = flagp[0] > 0.5f;
    int bq = blockIdx.x; int b = bq / NQ;
    int tid = threadIdx.x; int h = tid >> 5, d = tid & 31;
    __shared__ float sOff[256];
    __shared__ float sAw[128];
    __shared__ float sref[2];
    __shared__ float svr[8];
    sOff[tid] = off[(size_t)bq * 256 + tid];
    if (tid < 128) sAw[tid] = aw[(size_t)bq * 128 + tid];
    if (tid < 2)   sref[tid] = ldv(refp, bq * 2 + tid, 2, ef);
    if (tid < 8)   svr[tid]  = ldv(vr, b * 8 + tid, 2, ef);
    __syncthreads();
    const bf16* vb = value + (size_t)b * NS * DM + h * DHEAD + d;
    const int HS[4] = {100, 50, 25, 13};
    const int ST[4] = {0, 10000, 12500, 13125};
    float acc = 0.f;
    #pragma unroll
    for (int lvl = 0; lvl < 4; lvl++) {
        int W_ = HS[lvl], H_ = HS[lvl], st = ST[lvl];
        float rx = sref[0] * svr[lvl*2 + 0] * (float)W_;
        float ry = sref[1] * svr[lvl*2 + 1] * (float)H_;
        #pragma unroll
        for (int p = 0; p < 4; p++) {
            int oi = h * 32 + lvl * 8 + p * 2;
            float x = fminf(fmaxf(rx + sOff[oi]     - 0.5f, -4.f), (float)W_ + 4.f);
            float y = fminf(fmaxf(ry + sOff[oi + 1] - 0.5f, -4.f), (float)H_ + 4.f);
            float x0f = floorf(x), y0f = floorf(y);
            float wx = x - x0f, wy = y - y0f;
            int x0 = (int)x0f, y0 = (int)y0f;
            int x1i = x0 + 1, y1i = y0 + 1;
            bool vx0 = (x0 >= 0) && (x0 < W_), vx1 = (x1i >= 0) && (x1i < W_);
            bool vy0 = (y0 >= 0) && (y0 < H_), vy1 = (y1i >= 0) && (y1i < H_);
            float g = 0.f;
            if (vy0) {
                int rowo = (st + y0 * W_) * DM;
                if (vx0) g += (1.f - wx) * (1.f - wy) * __bfloat162float(vb[rowo + x0  * DM]);
                if (vx1) g += wx         * (1.f - wy) * __bfloat162float(vb[rowo + x1i * DM]);
            }
            if (vy1) {
                int rowo = (st + y1i * W_) * DM;
                if (vx0) g += (1.f - wx) * wy * __bfloat162float(vb[rowo + x0  * DM]);
                if (vx1) g += wx         * wy * __bfloat162float(vb[rowo + x1i * DM]);
            }
            acc += g * sAw[h * 16 + lvl * 4 + p];
        }
    }
    out[(size_t)bq * DM + tid] = acc;
}

// ---------------------------------------------------------------------------
__global__ __launch_bounds__(256) void copy_refs(const void* __restrict__ refp,
        void* __restrict__ out, const float* __restrict__ flagp)
{
    const bool ef = flagp[0] > 0.5f;
    int i = blockIdx.x * 256 + threadIdx.x;
    if (i >= NLAY * BQ * 2) return;
    float v = ldv(refp, i % (BQ * 2), 2, ef);
    size_t oi = (size_t)NLAY * BQ * DM + i;
    if (ef) ((float*)out)[oi] = v;
    else    ((bf16*)out)[oi] = __float2bfloat16(v);
}

// ---------------------------------------------------------------------------
extern "C" void kernel_launch(void* const* d_in, const int* in_sizes, int n_in,
                              void* d_out, int out_size, void* d_ws, size_t ws_size,
                              hipStream_t stream)
{
    const void* tgt     = d_in[0];
    const void* refp    = d_in[1];
    const void* memory  = d_in[2];
    const void* vr      = d_in[5];
    const void* qp      = d_in[6];
    const void* sa_in_w = d_in[7];
    const void* sa_in_b = d_in[8];
    const void* sa_out_w= d_in[9];
    const void* sa_out_b= d_in[10];
    const void* n1_g    = d_in[11];
    const void* n1_b    = d_in[12];
    const void* n2_g    = d_in[13];
    const void* n2_b    = d_in[14];
    const void* n3_g    = d_in[15];
    const void* n3_b    = d_in[16];
    const void* vp_w    = d_in[17];
    const void* vp_b    = d_in[18];
    const void* so_w    = d_in[19];
    const void* so_b    = d_in[20];
    const void* aw_w    = d_in[21];
    const void* aw_b    = d_in[22];
    const void* op_w    = d_in[23];
    const void* op_b    = d_in[24];
    const void* ff1_w   = d_in[25];
    const void* ff1_b   = d_in[26];
    const void* ff2_w   = d_in[27];
    const void* ff2_b   = d_in[28];

    // ---- workspace layout ----
    char* w = (char*)d_ws;
    float* flagp  = (float*)w;  w += 256;
    bf16*  value  = (bf16*)w;   w += (size_t)NB * NS * DM * 2;   // 54.45 MB
    float* outbuf = (float*)w;  w += (size_t)BQ * DM * 4;
    float* x1samp = (float*)w;  w += (size_t)BQ * DM * 4;        // x1, later samp
    bf16*  bigb   = (bf16*)w;   w += (size_t)BQ * NFF * 2;       // qkv / ffn hidden
    float* attoff = (float*)w;  w += (size_t)BQ * DM * 4;        // attn, later offsets
    float* t2     = (float*)w;  w += (size_t)BQ * DM * 4;
    float* awb    = (float*)w;  w += (size_t)BQ * 128 * 4;

    const int gy = (BQ + 63) / 64;      // 113
    const int MV = NB * NS;             // 106352

    // 0) detect external dtype
    detect_dtype<<<1, 256, 0, stream>>>(tgt, flagp);

    // 1) value projection (layer-invariant)
    gemm_mfma<<<dim3(DM/64, (MV + 63) / 64), 256, 0, stream>>>(
        memory, 2, vp_w, vp_b, value, 1, MV, DM, DM, 0, flagp);

    // 2) inter_refs output
    copy_refs<<<(NLAY * BQ * 2 + 255) / 256, 256, 0, stream>>>(refp, d_out, flagp);

    for (int l = 0; l < NLAY; l++) {
        // x1 = output + query_pos
        if (l == 0) add_qpos<<<BQ * DM / 256, 256, 0, stream>>>(tgt, 2, qp, x1samp, flagp);
        else        add_qpos<<<BQ * DM / 256, 256, 0, stream>>>(outbuf, 0, qp, x1samp, flagp);

        // self-attention
        gemm_mfma<<<dim3(768/64, gy), 256, 0, stream>>>(
            x1samp, 0, sa_in_w, sa_in_b, bigb, 1, BQ, 768, DM, 0, flagp);
        mha_mfma<<<dim3(15, NHEADS, NB), 256, 0, stream>>>(bigb, attoff);
        gemm_mfma<<<dim3(DM/64, gy), 256, 0, stream>>>(
            attoff, 0, sa_out_w, sa_out_b, t2, 0, BQ, DM, DM, 0, flagp);
        ln_kernel<<<BQ, 256, 0, stream>>>(x1samp, t2, n1_g, n1_b, outbuf,
                                          nullptr, 0, flagp);

        // MSDA
        gemm_mfma<<<dim3(DM/64, gy), 256, 0, stream>>>(
            outbuf, 0, so_w, so_b, attoff, 0, BQ, DM, DM, 0, flagp);
        gemm_mfma<<<dim3(128/64, gy), 256, 0, stream>>>(
            outbuf, 0, aw_w, aw_b, awb, 0, BQ, 128, DM, 0, flagp);
        aw_softmax<<<(BQ * NHEADS + 255) / 256, 256, 0, stream>>>(awb);
        msda_sample<<<BQ, 256, 0, stream>>>(value, attoff, awb, refp, vr, x1samp, flagp);
        gemm_mfma<<<dim3(DM/64, gy), 256, 0, stream>>>(
            x1samp, 0, op_w, op_b, t2, 0, BQ, DM, DM, 0, flagp);
        ln_kernel<<<BQ, 256, 0, stream>>>(outbuf, t2, n2_g, n2_b, outbuf,
                                          nullptr, 0, flagp);

        // FFN
        gemm_mfma<<<dim3(NFF/64, gy), 256, 0, stream>>>(
            outbuf, 0, ff1_w, ff1_b, bigb, 1, BQ, NFF, DM, 1, flagp);
        gemm_mfma<<<dim3(DM/64, gy), 256, 0, stream>>>(
            bigb, 1, ff2_w, ff2_b, t2, 0, BQ, DM, NFF, 0, flagp);
        ln_kernel<<<BQ, 256, 0, stream>>>(outbuf, t2, n3_g, n3_b, outbuf,
                                          d_out, (size_t)l * BQ * DM, flagp);
    }
}